// Round 21
// baseline (217.768 us; speedup 1.0000x reference)
//
#include <hip/hip_runtime.h>
#include <math.h>

#define T_LEN 4096
#define D_IN 128
#define KDIM 4096   // TR*CTX
#define K2   8192   // re+im

// ws float offsets
#define OFF_GATED 0u
#define OFF_GO    262144u
#define OFF_SKIP  524288u
#define OFF_LAM   786432u          // 4096 float2 = 8192 floats (lambda table)
#define OFF_FLAGS 4980736u         // 4096 ints
#define OFF_CHS   4984832u         // 64 ints
#define OFF_WZT   4984896u         // 524288 bf16 = 262144 float slots
#define OFF_SCR   5247040u         // carryB 524288 floats
#define OFF_CIN   5771328u         // cin scratch: 64*16*2*256 = 524288 floats

typedef __attribute__((ext_vector_type(8))) short short8v;
typedef __attribute__((ext_vector_type(4))) float float4v;

__device__ __forceinline__ float sigm(float x){ return 1.f/(1.f+expf(-x)); }
__device__ __forceinline__ unsigned short f2bf(float x){
    unsigned int u = __float_as_uint(x);
    return (unsigned short)((u + 0x7FFFu + ((u >> 16) & 1u)) >> 16);
}
__device__ __forceinline__ float wsum(float v) {
#pragma unroll
    for (int o = 32; o; o >>= 1) v += __shfl_xor(v, o, 64);
    return v;
}

// ---------------------------------------------------------------- prep: flags | wzt | mlp  (role by blockIdx)
__global__ __launch_bounds__(512) void k_prep(
    const unsigned char* __restrict__ su8, const int* __restrict__ si32,
    int* __restrict__ flags, int* __restrict__ chunkStart,
    const float* __restrict__ Wz, unsigned short* __restrict__ wzt,
    const float* __restrict__ x,
    const float* __restrict__ W1, const float* __restrict__ b1,
    const float* __restrict__ W2, const float* __restrict__ b2,
    const float* __restrict__ Wgi, const float* __restrict__ bgi,
    const float* __restrict__ Wp,  const float* __restrict__ bp,
    const float* __restrict__ Wgo, const float* __restrict__ bgo,
    const float* __restrict__ Wsk, const float* __restrict__ bsk,
    float* __restrict__ gated, float* __restrict__ go, float* __restrict__ sk)
{
    const int bx = blockIdx.x;
    const int tid = threadIdx.x;

    if (bx == 0) {
        __shared__ int cnt;
        if (tid == 0) cnt = 0;
        __syncthreads();
        int local = 0;
        for (int i = tid; i < 4096; i += 512)
            if (i & 3) local += su8[i];
        if (local) atomicAdd(&cnt, local);
        __syncthreads();
        if (cnt > 0) { for (int i = tid; i < 4096; i += 512) flags[i] = su8[i] ? 1 : 0; }
        else         { for (int i = tid; i < 4096; i += 512) flags[i] = si32[i] ? 1 : 0; }
        __syncthreads();
        if (tid < 64) {
            int any = 0;
#pragma unroll 8
            for (int j = 0; j < 64; ++j) any |= flags[tid * 64 + j];
            chunkStart[tid] = any;
        }
        return;
    }
    if (bx <= 64) {   // wzt[j][k] = bf16(Wz[k][j])
        int idx = ((bx - 1) * 512 + tid) * 16;
        int j = idx >> 13, k0 = idx & 8191;
#pragma unroll
        for (int e = 0; e < 16; ++e) {
            int k = k0 + e;
            wzt[(size_t)j * K2 + k] = f2bf(Wz[(size_t)k * 64 + j]);
        }
        return;
    }

    // mlp: 8 rows per block, weights-in-VGPR
    __shared__ float xs[8][128];
    __shared__ float hs[8][64];
    __shared__ float h2s[8][128];
    __shared__ float tmp[8][4][64];
    const int t0 = (bx - 65) * 8;

    if (tid < 256) {
        int r = tid >> 5, kq = (tid & 31) << 2;
        *(float4*)&xs[r][kq] = *(const float4*)&x[(size_t)(t0 + r) * D_IN + kq];
    }

    const int j1 = tid >> 3, ks1 = tid & 7;
    float wr1[16];
#pragma unroll
    for (int kk = 0; kk < 16; ++kk) wr1[kk] = W1[(size_t)(ks1 * 16 + kk) * 64 + j1];
    const float bias1 = b1[j1];
    __syncthreads();
#pragma unroll
    for (int r = 0; r < 8; ++r) {
        float p = 0.f;
#pragma unroll
        for (int kq = 0; kq < 4; ++kq) {
            float4 xv = *(const float4*)&xs[r][ks1 * 16 + kq * 4];
            p += xv.x*wr1[kq*4] + xv.y*wr1[kq*4+1] + xv.z*wr1[kq*4+2] + xv.w*wr1[kq*4+3];
        }
        p += __shfl_xor(p, 1, 64); p += __shfl_xor(p, 2, 64); p += __shfl_xor(p, 4, 64);
        if (ks1 == 0) hs[r][j1] = fmaxf(p + bias1, 0.f);
    }
    __syncthreads();

    const int j2 = tid >> 2, ks2 = tid & 3;
    float wr2[16];
#pragma unroll
    for (int kk = 0; kk < 16; ++kk) wr2[kk] = W2[(size_t)(ks2 * 16 + kk) * 128 + j2];
    const float bias2 = b2[j2];
#pragma unroll
    for (int r = 0; r < 8; ++r) {
        float p = 0.f;
#pragma unroll
        for (int kq = 0; kq < 4; ++kq) {
            float4 hv = *(const float4*)&hs[r][ks2 * 16 + kq * 4];
            p += hv.x*wr2[kq*4] + hv.y*wr2[kq*4+1] + hv.z*wr2[kq*4+2] + hv.w*wr2[kq*4+3];
        }
        p += __shfl_xor(p, 1, 64); p += __shfl_xor(p, 2, 64);
        if (ks2 == 0) h2s[r][j2] = p + bias2;
    }
    __syncthreads();

    const int mat = tid >> 7, jj = (tid & 127) >> 1, kh = tid & 1;
    const float* Wm = (mat == 0) ? Wgi : (mat == 1) ? Wp : (mat == 2) ? Wgo : Wsk;
    float wgr[64];
#pragma unroll
    for (int kk = 0; kk < 64; ++kk) wgr[kk] = Wm[(size_t)(kh * 64 + kk) * 64 + jj];
#pragma unroll
    for (int r = 0; r < 8; ++r) {
        float p = 0.f;
#pragma unroll
        for (int kq = 0; kq < 16; ++kq) {
            float4 hv = *(const float4*)&h2s[r][kh * 64 + kq * 4];
            p += hv.x*wgr[kq*4] + hv.y*wgr[kq*4+1] + hv.z*wgr[kq*4+2] + hv.w*wgr[kq*4+3];
        }
        p += __shfl_xor(p, 1, 64);
        if (kh == 0) tmp[r][mat][jj] = p;
    }
    __syncthreads();

    {
        int r = tid >> 6, j = tid & 63;
        int t = t0 + r;
        float gi = sigm(tmp[r][0][j] + bgi[j]);
        float pr = sigm(tmp[r][1][j] + bp[j]);
        float g  = sigm(tmp[r][2][j] + bgo[j]);
        float s  = tmp[r][3][j] + bsk[j];
        gated[t * 64 + j] = gi * pr;
        go[t * 64 + j]    = g;
        sk[t * 64 + j]    = s;
    }
}

// ---------------------------------------------------------------- scan A: per-chunk local carries, f32 + lambda table
__global__ __launch_bounds__(512) void k_scanA(
    const float* __restrict__ gated, const int* __restrict__ flags,
    const float* __restrict__ a, const float* __restrict__ b,
    float2* __restrict__ carryB, float2* __restrict__ lam)
{
    const int p = threadIdx.x >> 6, c = threadIdx.x & 63;
    const int pair = blockIdx.x * 8 + p;
    const int ch = pair & 63, m = pair >> 6;
    const int t0 = ch * 64;

    const double ead = exp(-fabs((double)a[m]));
    const double bbd = (double)b[c];
    const float lre = (float)(ead * cos(bbd)), lim = (float)(ead * sin(bbd));
    if (ch == 0) lam[m * 64 + c] = make_float2(lre, lim);
    unsigned long long fmask = __ballot(flags[t0 + c] != 0);
    const float* grow = gated + (size_t)t0 * 64 + m;   // wave-uniform base
    float sre = 0.f, sim = 0.f;
#pragma unroll 8
    for (int j = 0; j < 64; ++j) {
        float g = grow[j * 64];                         // wave-uniform -> s_load
        if ((fmask >> j) & 1) { sre = g; sim = 0.f; }
        else {
            float nr = fmaf(sre, lre, fmaf(-sim, lim, g));
            float ni = fmaf(sre, lim, sim * lre);
            sre = nr; sim = ni;
        }
    }
    carryB[(size_t)ch * KDIM + m * 64 + c] = make_float2(sre, sim);
}

// ---------------------------------------------------------------- scanZepi: one block per chunk
// prefix(16-wide ILP) -> 16 passes {scan -> tile -> MFMA-accumulate} -> in-block LN+W3+W4
// grid: 64 blocks (ch); 256 thr = 4 waves (ml) x 64 lanes (c)
__global__ __launch_bounds__(256, 1) void k_scanZepi(
    const float* __restrict__ gated, const int* __restrict__ flags,
    const int* __restrict__ chs,
    const float* __restrict__ st0, const float2* __restrict__ lam,
    const float2* __restrict__ carryB,
    const unsigned short* __restrict__ wzt,
    const float* __restrict__ go, const float* __restrict__ sk,
    const float* __restrict__ bz,
    const float* __restrict__ W3, const float* __restrict__ b3,
    const float* __restrict__ W4, const float* __restrict__ b4,
    float* __restrict__ cinW,
    float* __restrict__ out)
{
    const int tid = threadIdx.x;
    const int ml = tid >> 6, c = tid & 63, l = c;
    const int ch = blockIdx.x, t0 = ch * 64;
    __shared__ __align__(16) char smem[65536];
    unsigned short* st = (unsigned short*)smem;

    unsigned long long cmask = __ballot(chs[c] != 0);
    unsigned long long fmask = __ballot(flags[t0 + c] != 0);

    // ---- lambda^64 per m-group (6 f32 squarings) + cin seed from st0
    float cinr[16], cini[16], l64r[16], l64i[16];
#pragma unroll
    for (int mg = 0; mg < 16; ++mg) {
        int mm = mg * 4 + ml;
        float2 lv = lam[mm * 64 + c];
        float ar = lv.x, ai = lv.y;
#pragma unroll
        for (int s = 0; s < 6; ++s) { float nr = ar*ar - ai*ai; float ni = 2.f*ar*ai; ar = nr; ai = ni; }
        l64r[mg] = ar; l64i[mg] = ai;
        cinr[mg] = st0[(mm * 64 + c) * 2];
        cini[mg] = st0[(mm * 64 + c) * 2 + 1];
    }

    // ---- carry prefix over chunks < ch: 16 independent chains (ILP), 2-chunk load pipeline
    {
        float2 A0[16], A1[16];
        int chp = 0;
        for (; chp + 1 < ch; chp += 2) {
#pragma unroll
            for (int mg = 0; mg < 16; ++mg) A0[mg] = carryB[(size_t)chp * KDIM + (mg*4+ml)*64 + c];
#pragma unroll
            for (int mg = 0; mg < 16; ++mg) A1[mg] = carryB[(size_t)(chp+1) * KDIM + (mg*4+ml)*64 + c];
            const bool s0 = (cmask >> chp) & 1;
            const bool s1 = (cmask >> (chp + 1)) & 1;
#pragma unroll
            for (int mg = 0; mg < 16; ++mg) {
                if (s0) { cinr[mg] = A0[mg].x; cini[mg] = A0[mg].y; }
                else {
                    float nr = fmaf(cinr[mg], l64r[mg], fmaf(-cini[mg], l64i[mg], A0[mg].x));
                    float ni = fmaf(cinr[mg], l64i[mg], fmaf(cini[mg], l64r[mg], A0[mg].y));
                    cinr[mg] = nr; cini[mg] = ni;
                }
            }
#pragma unroll
            for (int mg = 0; mg < 16; ++mg) {
                if (s1) { cinr[mg] = A1[mg].x; cini[mg] = A1[mg].y; }
                else {
                    float nr = fmaf(cinr[mg], l64r[mg], fmaf(-cini[mg], l64i[mg], A1[mg].x));
                    float ni = fmaf(cinr[mg], l64i[mg], fmaf(cini[mg], l64r[mg], A1[mg].y));
                    cinr[mg] = nr; cini[mg] = ni;
                }
            }
        }
        if (chp < ch) {
#pragma unroll
            for (int mg = 0; mg < 16; ++mg) A0[mg] = carryB[(size_t)chp * KDIM + (mg*4+ml)*64 + c];
            const bool s0 = (cmask >> chp) & 1;
#pragma unroll
            for (int mg = 0; mg < 16; ++mg) {
                if (s0) { cinr[mg] = A0[mg].x; cini[mg] = A0[mg].y; }
                else {
                    float nr = fmaf(cinr[mg], l64r[mg], fmaf(-cini[mg], l64i[mg], A0[mg].x));
                    float ni = fmaf(cinr[mg], l64i[mg], fmaf(cini[mg], l64r[mg], A0[mg].y));
                    cinr[mg] = nr; cini[mg] = ni;
                }
            }
        }
    }

    // ---- stash cin to ws scratch (re-read per pass; keeps static reg indexing)
    float* cb = cinW + (size_t)ch * 8192;
#pragma unroll
    for (int mg = 0; mg < 16; ++mg) {
        cb[(mg * 2 + 0) * 256 + ml * 64 + c] = cinr[mg];
        cb[(mg * 2 + 1) * 256 + ml * 64 + c] = cini[mg];
    }

    // ---- 16 passes: seeded scan -> bf16 tile -> MFMA accumulate
    float4v acc[4];
#pragma unroll
    for (int i = 0; i < 4; ++i) acc[i] = (float4v){0.f, 0.f, 0.f, 0.f};
    const int e0 = ml * 128 + c, e1 = e0 + 64;
#pragma unroll 1
    for (int mg = 0; mg < 16; ++mg) {
        const int mm = mg * 4 + ml;
        float2 lv = lam[mm * 64 + c];
        const float lre = lv.x, lim = lv.y;
        short8v bfr[16];
#pragma unroll
        for (int ks = 0; ks < 16; ++ks)
            bfr[ks] = *(const short8v*)&wzt[(size_t)(ml*16 + (l&15)) * K2 + mg*512 + (ks*4 + (l>>4))*8];
        float cre = cb[(mg * 2 + 0) * 256 + ml * 64 + c];
        float cim = cb[(mg * 2 + 1) * 256 + ml * 64 + c];
        const float* grow = gated + (size_t)t0 * 64 + mm;   // wave-uniform base
#pragma unroll 4
        for (int j = 0; j < 64; ++j) {
            float g = grow[j * 64];                          // wave-uniform -> s_load
            if ((fmask >> j) & 1) { cre = g; cim = 0.f; }
            else {
                float nr = fmaf(cre, lre, fmaf(-cim, lim, g));
                float ni = fmaf(cre, lim, cim * lre);
                cre = nr; cim = ni;
            }
            const int sx = (j & 7) << 3;
            st[j * 512 + (e0 ^ sx)] = f2bf(cre);
            st[j * 512 + (e1 ^ sx)] = f2bf(cim);
        }
        if (ch == 63) {   // t = 4095: final state, planar f32
            out[524288 + mm * 64 + c]        = cre;
            out[524288 + 4096 + mm * 64 + c] = cim;
        }
        __syncthreads();
#pragma unroll
        for (int ks = 0; ks < 16; ++ks)
#pragma unroll
            for (int mt = 0; mt < 4; ++mt) {
                const int row = mt * 16 + (l & 15);
                const int rchunk = (ks * 4 + (l >> 4)) ^ (row & 7);
                short8v af = *(const short8v*)&st[row * 512 + rchunk * 8];
                acc[mt] = __builtin_amdgcn_mfma_f32_16x16x32_bf16(af, bfr[ks], acc[mt], 0, 0, 0);
            }
        __syncthreads();
    }

    // ---- epilogue in-block: z -> LN -> W3 -> W4
    const int j3 = tid >> 2, ks3 = tid & 3;
    float wgr3[16];
#pragma unroll
    for (int kk = 0; kk < 16; ++kk) wgr3[kk] = W3[(size_t)(ks3 * 16 + kk) * 64 + j3];
    const float b3v = b3[j3];
    const int j4 = tid >> 1, kh = tid & 1;
    float wgr4[32];
#pragma unroll
    for (int kk = 0; kk < 32; ++kk) wgr4[kk] = W4[(size_t)(kh * 32 + kk) * 128 + j4];
    const float b4v = b4[j4];

    float (*zb)[64] = (float(*)[64])smem;              // 16KB
    float (*ob)[64] = (float(*)[64])(smem + 16384);    // 16KB
    float (*hb)[64] = (float(*)[64])(smem + 32768);    // 16KB
    const int jcol = ml * 16 + (l & 15);
#pragma unroll
    for (int mt = 0; mt < 4; ++mt) {
        const int tr = mt * 16 + (l >> 4) * 4;
#pragma unroll
        for (int r = 0; r < 4; ++r) zb[tr + r][jcol] = acc[mt][r];
    }
    __syncthreads();

    // LN: wave ml handles rows it*4+ml
#pragma unroll
    for (int it = 0; it < 16; ++it) {
        const int r = it * 4 + ml, t = t0 + r;
        float z = zb[r][c] + bz[c];
        float g = go[t * 64 + c];
        float y = z * g;
        float mu = wsum(y) * 0.015625f;
        float d = y - mu;
        float var = wsum(d * d) * 0.015625f;
        ob[r][c] = d * (1.f / sqrtf(var + 1e-6f)) + sk[t * 64 + c] * (1.f - g);
    }
    __syncthreads();

    // W3: relu(ob @ W3 + b3)
#pragma unroll 4
    for (int r = 0; r < 64; ++r) {
        float p = 0.f;
#pragma unroll
        for (int kq = 0; kq < 4; ++kq) {
            float4 v = *(const float4*)&ob[r][ks3 * 16 + kq * 4];
            p += v.x*wgr3[kq*4] + v.y*wgr3[kq*4+1] + v.z*wgr3[kq*4+2] + v.w*wgr3[kq*4+3];
        }
        p += __shfl_xor(p, 1, 64); p += __shfl_xor(p, 2, 64);
        if (ks3 == 0) hb[r][j3] = fmaxf(p + b3v, 0.f);
    }
    __syncthreads();

    // W4: out = hb @ W4 + b4
#pragma unroll 4
    for (int r = 0; r < 64; ++r) {
        float p = 0.f;
#pragma unroll
        for (int kq = 0; kq < 8; ++kq) {
            float4 v = *(const float4*)&hb[r][kh * 32 + kq * 4];
            p += v.x*wgr4[kq*4] + v.y*wgr4[kq*4+1] + v.z*wgr4[kq*4+2] + v.w*wgr4[kq*4+3];
        }
        p += __shfl_xor(p, 1, 64);
        if (kh == 0) out[(size_t)(t0 + r) * 128 + j4] = p + b4v;
    }
}

// ----------------------------------------------------------------
extern "C" void kernel_launch(void* const* d_in, const int* in_sizes, int n_in,
                              void* d_out, int out_size, void* d_ws, size_t ws_size,
                              hipStream_t stream)
{
    const float* x   = (const float*)d_in[0];
    const float* st0 = (const float*)d_in[1];
    const void*  start = d_in[2];
    const float* a  = (const float*)d_in[3];
    const float* b  = (const float*)d_in[4];
    const float* W1 = (const float*)d_in[5];  const float* b1 = (const float*)d_in[6];
    const float* W2 = (const float*)d_in[7];  const float* b2 = (const float*)d_in[8];
    const float* Wgi= (const float*)d_in[9];  const float* bgi= (const float*)d_in[10];
    const float* Wp = (const float*)d_in[11]; const float* bp = (const float*)d_in[12];
    const float* Wz = (const float*)d_in[13]; const float* bz = (const float*)d_in[14];
    const float* Wgo= (const float*)d_in[15]; const float* bgo= (const float*)d_in[16];
    const float* Wsk= (const float*)d_in[17]; const float* bsk= (const float*)d_in[18];
    const float* W3 = (const float*)d_in[19]; const float* b3 = (const float*)d_in[20];
    const float* W4 = (const float*)d_in[21]; const float* b4 = (const float*)d_in[22];

    float* ws    = (float*)d_ws;
    float* out   = (float*)d_out;
    float* gated = ws + OFF_GATED;
    float* go    = ws + OFF_GO;
    float* sk    = ws + OFF_SKIP;
    int*   flags = (int*)(ws + OFF_FLAGS);
    int*   chs   = (int*)(ws + OFF_CHS);
    unsigned short* wzt = (unsigned short*)(ws + OFF_WZT);
    float2* carryB = (float2*)(ws + OFF_SCR);
    float2* lam    = (float2*)(ws + OFF_LAM);
    float*  cinW   = ws + OFF_CIN;

    hipLaunchKernelGGL(k_prep, dim3(577), dim3(512), 0, stream,
                       (const unsigned char*)start, (const int*)start, flags, chs,
                       Wz, wzt, x, W1, b1, W2, b2, Wgi, bgi, Wp, bp,
                       Wgo, bgo, Wsk, bsk, gated, go, sk);
    hipLaunchKernelGGL(k_scanA, dim3(512), dim3(512), 0, stream,
                       gated, flags, a, b, carryB, lam);
    hipLaunchKernelGGL(k_scanZepi, dim3(64), dim3(256), 0, stream,
                       gated, flags, chs, st0, (const float2*)lam, (const float2*)carryB,
                       wzt, go, sk, bz, W3, b3, W4, b4, cinW, out);
}

// Round 22
// 76.507 us; speedup vs baseline: 2.8464x; 2.8464x over previous
//
#include <hip/hip_runtime.h>
#include <math.h>

#define T_LEN 4096
#define D_IN 128
#define KDIM 4096   // TR*CTX
#define K2   8192   // re+im

// ws float offsets
#define OFF_GATED 0u
#define OFF_GO    262144u
#define OFF_SKIP  524288u
#define OFF_PART  786432u          // 16 * 262144 partials
#define OFF_FLAGS 4980736u         // 4096 ints
#define OFF_CHS   4984832u         // 64 ints
#define OFF_WZT   4984896u         // 524288 bf16 = 262144 float slots
#define OFF_SCR   5247040u         // carryB 524288 floats

typedef __attribute__((ext_vector_type(8))) short short8v;
typedef __attribute__((ext_vector_type(4))) float float4v;

__device__ __forceinline__ float sigm(float x){ return 1.f/(1.f+expf(-x)); }
__device__ __forceinline__ unsigned short f2bf(float x){
    unsigned int u = __float_as_uint(x);
    return (unsigned short)((u + 0x7FFFu + ((u >> 16) & 1u)) >> 16);
}
__device__ __forceinline__ float wsum(float v) {
#pragma unroll
    for (int o = 32; o; o >>= 1) v += __shfl_xor(v, o, 64);
    return v;
}

// ---------------------------------------------------------------- prep: flags | wzt | mlp  (role by blockIdx)
__global__ __launch_bounds__(512) void k_prep(
    const unsigned char* __restrict__ su8, const int* __restrict__ si32,
    int* __restrict__ flags, int* __restrict__ chunkStart,
    const float* __restrict__ Wz, unsigned short* __restrict__ wzt,
    const float* __restrict__ x,
    const float* __restrict__ W1, const float* __restrict__ b1,
    const float* __restrict__ W2, const float* __restrict__ b2,
    const float* __restrict__ Wgi, const float* __restrict__ bgi,
    const float* __restrict__ Wp,  const float* __restrict__ bp,
    const float* __restrict__ Wgo, const float* __restrict__ bgo,
    const float* __restrict__ Wsk, const float* __restrict__ bsk,
    float* __restrict__ gated, float* __restrict__ go, float* __restrict__ sk)
{
    const int bx = blockIdx.x;
    const int tid = threadIdx.x;

    if (bx == 0) {
        __shared__ int cnt;
        if (tid == 0) cnt = 0;
        __syncthreads();
        int local = 0;
        for (int i = tid; i < 4096; i += 512)
            if (i & 3) local += su8[i];
        if (local) atomicAdd(&cnt, local);
        __syncthreads();
        if (cnt > 0) { for (int i = tid; i < 4096; i += 512) flags[i] = su8[i] ? 1 : 0; }
        else         { for (int i = tid; i < 4096; i += 512) flags[i] = si32[i] ? 1 : 0; }
        __syncthreads();
        if (tid < 64) {
            int any = 0;
#pragma unroll 8
            for (int j = 0; j < 64; ++j) any |= flags[tid * 64 + j];
            chunkStart[tid] = any;
        }
        return;
    }
    if (bx <= 64) {   // wzt[j][k] = bf16(Wz[k][j])
        int idx = ((bx - 1) * 512 + tid) * 16;
        int j = idx >> 13, k0 = idx & 8191;
#pragma unroll
        for (int e = 0; e < 16; ++e) {
            int k = k0 + e;
            wzt[(size_t)j * K2 + k] = f2bf(Wz[(size_t)k * 64 + j]);
        }
        return;
    }

    // mlp: 8 rows per block, weights-in-VGPR
    __shared__ float xs[8][128];
    __shared__ float hs[8][64];
    __shared__ float h2s[8][128];
    __shared__ float tmp[8][4][64];
    const int t0 = (bx - 65) * 8;

    if (tid < 256) {
        int r = tid >> 5, kq = (tid & 31) << 2;
        *(float4*)&xs[r][kq] = *(const float4*)&x[(size_t)(t0 + r) * D_IN + kq];
    }

    const int j1 = tid >> 3, ks1 = tid & 7;
    float wr1[16];
#pragma unroll
    for (int kk = 0; kk < 16; ++kk) wr1[kk] = W1[(size_t)(ks1 * 16 + kk) * 64 + j1];
    const float bias1 = b1[j1];
    __syncthreads();
#pragma unroll
    for (int r = 0; r < 8; ++r) {
        float p = 0.f;
#pragma unroll
        for (int kq = 0; kq < 4; ++kq) {
            float4 xv = *(const float4*)&xs[r][ks1 * 16 + kq * 4];
            p += xv.x*wr1[kq*4] + xv.y*wr1[kq*4+1] + xv.z*wr1[kq*4+2] + xv.w*wr1[kq*4+3];
        }
        p += __shfl_xor(p, 1, 64); p += __shfl_xor(p, 2, 64); p += __shfl_xor(p, 4, 64);
        if (ks1 == 0) hs[r][j1] = fmaxf(p + bias1, 0.f);
    }
    __syncthreads();

    const int j2 = tid >> 2, ks2 = tid & 3;
    float wr2[16];
#pragma unroll
    for (int kk = 0; kk < 16; ++kk) wr2[kk] = W2[(size_t)(ks2 * 16 + kk) * 128 + j2];
    const float bias2 = b2[j2];
#pragma unroll
    for (int r = 0; r < 8; ++r) {
        float p = 0.f;
#pragma unroll
        for (int kq = 0; kq < 4; ++kq) {
            float4 hv = *(const float4*)&hs[r][ks2 * 16 + kq * 4];
            p += hv.x*wr2[kq*4] + hv.y*wr2[kq*4+1] + hv.z*wr2[kq*4+2] + hv.w*wr2[kq*4+3];
        }
        p += __shfl_xor(p, 1, 64); p += __shfl_xor(p, 2, 64);
        if (ks2 == 0) h2s[r][j2] = p + bias2;
    }
    __syncthreads();

    const int mat = tid >> 7, jj = (tid & 127) >> 1, kh = tid & 1;
    const float* Wm = (mat == 0) ? Wgi : (mat == 1) ? Wp : (mat == 2) ? Wgo : Wsk;
    float wgr[64];
#pragma unroll
    for (int kk = 0; kk < 64; ++kk) wgr[kk] = Wm[(size_t)(kh * 64 + kk) * 64 + jj];
#pragma unroll
    for (int r = 0; r < 8; ++r) {
        float p = 0.f;
#pragma unroll
        for (int kq = 0; kq < 16; ++kq) {
            float4 hv = *(const float4*)&h2s[r][kh * 64 + kq * 4];
            p += hv.x*wgr[kq*4] + hv.y*wgr[kq*4+1] + hv.z*wgr[kq*4+2] + hv.w*wgr[kq*4+3];
        }
        p += __shfl_xor(p, 1, 64);
        if (kh == 0) tmp[r][mat][jj] = p;
    }
    __syncthreads();

    {
        int r = tid >> 6, j = tid & 63;
        int t = t0 + r;
        float gi = sigm(tmp[r][0][j] + bgi[j]);
        float pr = sigm(tmp[r][1][j] + bp[j]);
        float g  = sigm(tmp[r][2][j] + bgo[j]);
        float s  = tmp[r][3][j] + bsk[j];
        gated[t * 64 + j] = gi * pr;
        go[t * 64 + j]    = g;
        sk[t * 64 + j]    = s;
    }
}

// ---------------------------------------------------------------- scan A: per-chunk local carries, f32 (8 chains/block)
__global__ __launch_bounds__(512) void k_scanA(
    const float* __restrict__ gated, const int* __restrict__ flags,
    const float* __restrict__ a, const float* __restrict__ b,
    float2* __restrict__ carryB)
{
    const int p = threadIdx.x >> 6, c = threadIdx.x & 63;
    const int pair = blockIdx.x * 8 + p;
    const int ch = pair & 63, m = pair >> 6;
    const int t0 = ch * 64;

    const double ead = exp(-fabs((double)a[m]));
    const double bbd = (double)b[c];
    const float lre = (float)(ead * cos(bbd)), lim = (float)(ead * sin(bbd));
    float gv = gated[(size_t)(t0 + c) * 64 + m];
    unsigned long long fmask = __ballot(flags[t0 + c] != 0);
    float sre = 0.f, sim = 0.f;
#pragma unroll 8
    for (int j = 0; j < 64; ++j) {
        float g = __shfl(gv, j, 64);
        if ((fmask >> j) & 1) { sre = g; sim = 0.f; }
        else {
            float nr = fmaf(sre, lre, fmaf(-sim, lim, g));
            float ni = fmaf(sre, lim, sim * lre);
            sre = nr; sim = ni;
        }
    }
    carryB[(size_t)ch * KDIM + m * 64 + c] = make_float2(sre, sim);
}

// ---------------------------------------------------------------- scanBZ2: f32 prefix + 2-chunk seeded scan -> LDS -> MFMA
// grid: 512 blocks = (chpair 0..31) x (mg 0..15); 256 thr = 4 waves (ml) x 64 lanes (c)
__global__ __launch_bounds__(256) void k_scanBZ2(
    const float* __restrict__ gated, const int* __restrict__ flags,
    const int* __restrict__ chs,
    const float* __restrict__ a, const float* __restrict__ b,
    const float* __restrict__ st0,
    const float2* __restrict__ carryB,
    const unsigned short* __restrict__ wzt,
    float* __restrict__ part,
    float* __restrict__ out)
{
    const int tid = threadIdx.x;
    const int ml = tid >> 6, c = tid & 63;       // ml = wave index
    const int chpair = blockIdx.x & 31, mg = blockIdx.x >> 5;
    const int ch0 = chpair * 2;
    const int m = mg * 4 + ml;
    __shared__ unsigned short st[64 * 512];      // 64KB, swizzled chunks of 8 elems

    // per-chain lambda (f64 transcendentals, f32 arithmetic)
    const double ead = exp(-fabs((double)a[m]));
    const double bbd = (double)b[c];
    const float lre = (float)(ead * cos(bbd)), lim = (float)(ead * sin(bbd));

    // ---- carry prefix to chunk ch0: batched f32, software-pipelined (no spill)
    unsigned long long cmask = __ballot(chs[c] != 0);
    const double ea64 = exp(-64.0 * fabs((double)a[m]));
    const float l64re = (float)(ea64 * cos(64.0 * bbd));
    const float l64im = (float)(ea64 * sin(64.0 * bbd));
    float cre = st0[(m * 64 + c) * 2];
    float cim = st0[(m * 64 + c) * 2 + 1];
    {
        const float2* cbase = carryB + m * 64 + c;
        float2 BA[16], BB[16];
#define LOADB(dst, base)                                          \
        _Pragma("unroll")                                         \
        for (int q = 0; q < 16; ++q)                              \
            dst[q] = cbase[(size_t)((base) + q) * KDIM];
#define COMB(src, base)                                           \
        _Pragma("unroll")                                         \
        for (int q = 0; q < 16; ++q) {                            \
            int chp = (base) + q;                                 \
            if (chp < ch0) {  /* wave-uniform scalar branch */    \
                if ((cmask >> chp) & 1) { cre = src[q].x; cim = src[q].y; } \
                else {                                            \
                    float nr = fmaf(cre, l64re, fmaf(-cim, l64im, src[q].x)); \
                    float ni = fmaf(cre, l64im, fmaf(cim, l64re, src[q].y)); \
                    cre = nr; cim = ni;                           \
                }                                                 \
            }                                                     \
        }
        if (ch0 > 0)  { LOADB(BA, 0) }
        if (ch0 > 16) { LOADB(BB, 16) }
        if (ch0 > 0)  { COMB(BA, 0) }
        if (ch0 > 32) { LOADB(BA, 32) }
        if (ch0 > 16) { COMB(BB, 16) }
        if (ch0 > 48) { LOADB(BB, 48) }
        if (ch0 > 32) { COMB(BA, 32) }
        if (ch0 > 48) { COMB(BB, 48) }
#undef LOADB
#undef COMB
    }

    // ---- B fragments (L2-hot), shared across both chunks
    const int l = c;
    const int jrow = ml * 16 + (l & 15);
    short8v bfr[16];
#pragma unroll
    for (int ks = 0; ks < 16; ++ks)
        bfr[ks] = *(const short8v*)&wzt[(size_t)jrow * K2 + mg * 512 + (ks * 4 + (l >> 4)) * 8];

    const int e0 = ml * 128 + c, e1 = e0 + 64;
    const int jcol = ml * 16 + (l & 15);

    for (int u = 0; u < 2; ++u) {
        const int ch = ch0 + u, t0s = ch * 64;

        // ---- seeded f32 scan; running carry continues exactly across the pair
        float gv = gated[(size_t)(t0s + c) * 64 + m];
        unsigned long long fmask = __ballot(flags[t0s + c] != 0);
#pragma unroll 4
        for (int j = 0; j < 64; ++j) {
            float g = __shfl(gv, j, 64);
            if ((fmask >> j) & 1) { cre = g; cim = 0.f; }
            else {
                float nr = fmaf(cre, lre, fmaf(-cim, lim, g));
                float ni = fmaf(cre, lim, cim * lre);
                cre = nr; cim = ni;
            }
            const int sx = (j & 7) << 3;
            st[j * 512 + (e0 ^ sx)] = f2bf(cre);
            st[j * 512 + (e1 ^ sx)] = f2bf(cim);
        }
        if (ch == 63) {   // t = 4095: final state, planar f32
            out[524288 + m * 64 + c]        = cre;
            out[524288 + 4096 + m * 64 + c] = cim;
        }
        __syncthreads();

        // ---- MFMA against the tile
        float4v acc[4];
#pragma unroll
        for (int i = 0; i < 4; ++i) acc[i] = (float4v){0.f, 0.f, 0.f, 0.f};
#pragma unroll
        for (int ks = 0; ks < 16; ++ks) {
#pragma unroll
            for (int mt = 0; mt < 4; ++mt) {
                const int row = mt * 16 + (l & 15);
                const int rchunk = (ks * 4 + (l >> 4)) ^ (row & 7);
                short8v af = *(const short8v*)&st[row * 512 + rchunk * 8];
                acc[mt] = __builtin_amdgcn_mfma_f32_16x16x32_bf16(af, bfr[ks], acc[mt], 0, 0, 0);
            }
        }

        // C/D: t-row = mt*16 + (lane>>4)*4 + r; j-col = ml*16 + (lane&15)
        float* pp = part + (size_t)mg * 262144;
#pragma unroll
        for (int mt = 0; mt < 4; ++mt) {
            const int trow = t0s + mt * 16 + (l >> 4) * 4;
#pragma unroll
            for (int r = 0; r < 4; ++r)
                pp[(size_t)(trow + r) * 64 + jcol] = acc[mt][r];
        }
        __syncthreads();   // tile reuse guard before next chunk's scan overwrites st
    }
}

// ---------------------------------------------------------------- epilogue
__global__ __launch_bounds__(256) void k_epi(
    const float* __restrict__ part, const float* __restrict__ bz,
    const float* __restrict__ go, const float* __restrict__ sk,
    const float* __restrict__ W3, const float* __restrict__ b3,
    const float* __restrict__ W4, const float* __restrict__ b4,
    float* __restrict__ out)
{
    __shared__ float ob[4][64], hb[4][64];
    const int w = threadIdx.x >> 6, j = threadIdx.x & 63;
    const int t = blockIdx.x * 4 + w;
    float z = bz[j];
#pragma unroll
    for (int p = 0; p < 16; ++p) z += part[(size_t)p * 262144 + t * 64 + j];
    float g = go[t * 64 + j];
    float y = z * g;
    float mu = wsum(y) * 0.015625f;
    float d = y - mu;
    float var = wsum(d * d) * 0.015625f;
    float o = d * (1.f / sqrtf(var + 1e-6f)) + sk[t * 64 + j] * (1.f - g);
    ob[w][j] = o;
    __syncthreads();
    float acc = b3[j];
#pragma unroll 8
    for (int k = 0; k < 64; ++k) acc += ob[w][k] * W3[k * 64 + j];
    hb[w][j] = fmaxf(acc, 0.f);
    __syncthreads();
    float o1 = b4[j], o2 = b4[j + 64];
#pragma unroll 8
    for (int k = 0; k < 64; ++k) { float hv = hb[w][k]; o1 += hv * W4[k * 128 + j]; o2 += hv * W4[k * 128 + j + 64]; }
    out[(size_t)t * 128 + j] = o1;
    out[(size_t)t * 128 + j + 64] = o2;
}

// ----------------------------------------------------------------
extern "C" void kernel_launch(void* const* d_in, const int* in_sizes, int n_in,
                              void* d_out, int out_size, void* d_ws, size_t ws_size,
                              hipStream_t stream)
{
    const float* x   = (const float*)d_in[0];
    const float* st0 = (const float*)d_in[1];
    const void*  start = d_in[2];
    const float* a  = (const float*)d_in[3];
    const float* b  = (const float*)d_in[4];
    const float* W1 = (const float*)d_in[5];  const float* b1 = (const float*)d_in[6];
    const float* W2 = (const float*)d_in[7];  const float* b2 = (const float*)d_in[8];
    const float* Wgi= (const float*)d_in[9];  const float* bgi= (const float*)d_in[10];
    const float* Wp = (const float*)d_in[11]; const float* bp = (const float*)d_in[12];
    const float* Wz = (const float*)d_in[13]; const float* bz = (const float*)d_in[14];
    const float* Wgo= (const float*)d_in[15]; const float* bgo= (const float*)d_in[16];
    const float* Wsk= (const float*)d_in[17]; const float* bsk= (const float*)d_in[18];
    const float* W3 = (const float*)d_in[19]; const float* b3 = (const float*)d_in[20];
    const float* W4 = (const float*)d_in[21]; const float* b4 = (const float*)d_in[22];

    float* ws    = (float*)d_ws;
    float* out   = (float*)d_out;
    float* gated = ws + OFF_GATED;
    float* go    = ws + OFF_GO;
    float* sk    = ws + OFF_SKIP;
    float* part  = ws + OFF_PART;
    int*   flags = (int*)(ws + OFF_FLAGS);
    int*   chs   = (int*)(ws + OFF_CHS);
    unsigned short* wzt = (unsigned short*)(ws + OFF_WZT);
    float2* carryB = (float2*)(ws + OFF_SCR);

    hipLaunchKernelGGL(k_prep, dim3(577), dim3(512), 0, stream,
                       (const unsigned char*)start, (const int*)start, flags, chs,
                       Wz, wzt, x, W1, b1, W2, b2, Wgi, bgi, Wp, bp,
                       Wgo, bgo, Wsk, bsk, gated, go, sk);
    hipLaunchKernelGGL(k_scanA, dim3(512), dim3(512), 0, stream,
                       gated, flags, a, b, carryB);
    hipLaunchKernelGGL(k_scanBZ2, dim3(512), dim3(256), 0, stream,
                       gated, flags, chs, a, b, st0, carryB, wzt, part, out);
    hipLaunchKernelGGL(k_epi, dim3(1024), dim3(256), 0, stream,
                       part, bz, go, sk, W3, b3, W4, b4, out);
}